// Round 16
// baseline (132.773 us; speedup 1.0000x reference)
//
#include <hip/hip_runtime.h>

// GraphSAGE 2-layer, fp32 in/out. N=100000, E=1.6M, D: 64 -> 64 -> 32.
// Transform-first on BOTH layers. t1l: fp8 (64 B rows), t2l: bf16, t1r: bf16.
// R16: un-bundled R15 -- bscatter reverted to R14's simple single-pass
// (R15's 33 KB LDS sort cut its occupancy 8->4 blk/CU); agg1+gemm2 fusion
// KEPT but sH stride changed 72->74 ushorts: old stride 144 B put every
// h-write on even banks (8-way, 2.65M conflict cycles); 74 gives bank
// 5*lm%32 on MFMA reads (all distinct) and minimum 4-way on writes.
// Aggs: 16-lane group/node, 8-deep chains. CSR: g1h(gemm1+bhist)->cscan->
// bscatter->bucket_csr.

typedef __attribute__((ext_vector_type(4))) float f4;
typedef __attribute__((ext_vector_type(2))) float f2;
typedef __attribute__((ext_vector_type(4))) unsigned short us4;
typedef __attribute__((ext_vector_type(8))) unsigned short us8;
typedef __attribute__((ext_vector_type(8))) short bfrag;   // 8 bf16 (4 VGPRs)

#define BSHIFT 9
#define BSZ (1 << BSHIFT)   // 512 nodes per bucket
#define NBMAX 256
#define NBLK 512            // histogram/scatter blocks (cntmat rows)
#define LSTR 72             // LDS row stride in ushorts (weights; 2-way reads free)
#define HSTR 74             // LDS row stride for sH (bank 5*lm%32: conflict-free reads)

static __device__ inline unsigned short f2bf(float f) {
    union { float f; unsigned u; } v; v.f = f;
    unsigned u = v.u;
    u = (u + 0x7FFFu + ((u >> 16) & 1u)) >> 16;   // RNE
    return (unsigned short)u;
}
static __device__ inline float bf2f(unsigned short h) {
    union { unsigned u; float f; } v; v.u = ((unsigned)h) << 16; return v.f;
}

// ---------------- Fused GEMM1 + bhist ----------------
__global__ __launch_bounds__(256) void k_g1h(const float* __restrict__ x,
                                             const float* __restrict__ Wl,
                                             const float* __restrict__ Wr, int N, int gb,
                                             unsigned char* __restrict__ t1l8,
                                             unsigned short* __restrict__ t1rb,
                                             const int* __restrict__ dst, int E, int chunk,
                                             int NB, int* __restrict__ cntmat) {
    __shared__ unsigned short smem[64 * LSTR + 128 * LSTR];   // 27.6 KB
    int t = threadIdx.x;
    if ((int)blockIdx.x >= gb) {
        int* hist = (int*)smem;
        hist[t] = 0;
        __syncthreads();
        int bb = blockIdx.x - gb;
        int lo = bb * chunk, hi = min(lo + chunk, E);
        for (int e = lo + t; e < hi; e += 256) atomicAdd(&hist[dst[e] >> BSHIFT], 1);
        __syncthreads();
        if (t < NB) cntmat[bb * NB + t] = hist[t];
        return;
    }
    unsigned short* sX = smem;              // [64][LSTR]
    unsigned short* sW = smem + 64 * LSTR;  // [128][LSTR]
    int r0 = blockIdx.x * 64;
    for (int i = t; i < 2048; i += 256) {
        int which = i >> 10;
        int rem = i & 1023;
        int k = rem >> 4;
        int c4 = (rem & 15) * 4;
        f4 v = *(const f4*)&(which ? Wr : Wl)[k * 64 + c4];
        int nb = which * 64 + c4;
        sW[(nb + 0) * LSTR + k] = f2bf(v[0]);
        sW[(nb + 1) * LSTR + k] = f2bf(v[1]);
        sW[(nb + 2) * LSTR + k] = f2bf(v[2]);
        sW[(nb + 3) * LSTR + k] = f2bf(v[3]);
    }
    {
        int row = t >> 2;
        int q = (t & 3) * 16;
        bool valid = (r0 + row) < N;
#pragma unroll
        for (int j = 0; j < 4; j++) {
            f4 v = {0.f, 0.f, 0.f, 0.f};
            if (valid) v = *(const f4*)&x[(size_t)(r0 + row) * 64 + q + j * 4];
            us4 bv;
            bv[0] = f2bf(v[0]); bv[1] = f2bf(v[1]); bv[2] = f2bf(v[2]); bv[3] = f2bf(v[3]);
            *(us4*)&sX[row * LSTR + q + j * 4] = bv;
        }
    }
    __syncthreads();
    int wv = t >> 6;
    int l  = t & 63;
    int lm = l & 15;
    int lk = (l >> 4) * 8;
    f4 acc[8] = {{0.f,0.f,0.f,0.f},{0.f,0.f,0.f,0.f},{0.f,0.f,0.f,0.f},{0.f,0.f,0.f,0.f},
                 {0.f,0.f,0.f,0.f},{0.f,0.f,0.f,0.f},{0.f,0.f,0.f,0.f},{0.f,0.f,0.f,0.f}};
#pragma unroll
    for (int kh = 0; kh < 2; kh++) {
        bfrag a = *(const bfrag*)&sX[(wv * 16 + lm) * LSTR + kh * 32 + lk];
#pragma unroll
        for (int nt = 0; nt < 8; nt++) {
            bfrag b = *(const bfrag*)&sW[(nt * 16 + lm) * LSTR + kh * 32 + lk];
            acc[nt] = __builtin_amdgcn_mfma_f32_16x16x32_bf16(a, b, acc[nt], 0, 0, 0);
        }
    }
    int orow0 = r0 + wv * 16 + (l >> 4) * 4;
#pragma unroll
    for (int j = 0; j < 4; j++) {
        int rr = orow0 + j;
        if (rr < N) {
#pragma unroll
            for (int nt = 0; nt < 4; nt++) {
                float v = acc[nt][j];
                unsigned w8 = __builtin_amdgcn_cvt_pk_fp8_f32(v, v, 0u, false);
                t1l8[(size_t)rr * 64 + nt * 16 + lm] = (unsigned char)(w8 & 0xFFu);
            }
#pragma unroll
            for (int nt = 0; nt < 4; nt++) {
                t1rb[(size_t)rr * 64 + nt * 16 + lm] = f2bf(acc[nt + 4][j]);
            }
        }
    }
}

// ---------------- cscan ----------------
__global__ __launch_bounds__(256) void k_cscan(int* __restrict__ cntmat, int NB, int E, int N,
                                               int* __restrict__ btot, int* __restrict__ row_off) {
    __shared__ int wt[4];
    int b = blockIdx.x;
    int t = threadIdx.x;
    int v0 = cntmat[(2 * t) * NB + b];
    int v1 = cntmat[(2 * t + 1) * NB + b];
    int tsum = v0 + v1;
    int lane = t & 63, w = t >> 6;
    int p = tsum;
    for (int off = 1; off < 64; off <<= 1) { int u = __shfl_up(p, off); if (lane >= off) p += u; }
    if (lane == 63) wt[w] = p;
    __syncthreads();
    int wb = 0;
    for (int i = 0; i < w; i++) wb += wt[i];
    int excl = wb + p - tsum;
    cntmat[(2 * t) * NB + b] = excl;
    cntmat[(2 * t + 1) * NB + b] = excl + v0;
    if (t == 255) btot[b] = wb + p;
    if (b == 0 && t == 0) row_off[N] = E;
}

// ---------------- bscatter: single-pass (R14 proven) ----------------
__global__ __launch_bounds__(256) void k_bscatter(const int* __restrict__ src, const int* __restrict__ dst,
                                                  int E, int chunk, int NB,
                                                  const int* __restrict__ btot,
                                                  const int* __restrict__ cntmat,
                                                  unsigned int* __restrict__ bdata) {
    __shared__ int lbase[NBMAX], lcur[NBMAX];
    __shared__ int wt[4];
    int t = threadIdx.x;
    int v = (t < NB) ? btot[t] : 0;
    int lane = t & 63, w = t >> 6;
    int p = v;
    for (int off = 1; off < 64; off <<= 1) { int u = __shfl_up(p, off); if (lane >= off) p += u; }
    if (lane == 63) wt[w] = p;
    __syncthreads();
    int wb = 0;
    for (int i = 0; i < w; i++) wb += wt[i];
    int excl = wb + p - v;
    if (t < NB) { lbase[t] = excl + cntmat[blockIdx.x * NB + t]; lcur[t] = 0; }
    __syncthreads();
    int lo = blockIdx.x * chunk, hi = min(lo + chunk, E);
    for (int e = lo + t; e < hi; e += 256) {
        int d = dst[e];
        int b = d >> BSHIFT;
        int pos = lbase[b] + atomicAdd(&lcur[b], 1);
        bdata[pos] = ((unsigned)(d & (BSZ - 1)) << 17) | (unsigned)src[e];  // src < 2^17
    }
}

// ---------------- bucket_csr ----------------
__global__ __launch_bounds__(256) void k_bucket_csr(const unsigned int* __restrict__ bdata,
                                                    const int* __restrict__ btot, int NB,
                                                    int N, int* __restrict__ row_off,
                                                    int* __restrict__ col_src) {
    __shared__ int fh[BSZ];
    __shared__ int wt1[4], wt2[4];
    __shared__ int sb[2];
    int t = threadIdx.x;
    int b = blockIdx.x;
    {
        int v = (t < NB) ? btot[t] : 0;
        int lane = t & 63, w = t >> 6;
        int p = v;
        for (int off = 1; off < 64; off <<= 1) { int u = __shfl_up(p, off); if (lane >= off) p += u; }
        if (lane == 63) wt1[w] = p;
        __syncthreads();
        int wb = 0;
        for (int i = 0; i < w; i++) wb += wt1[i];
        int excl = wb + p - v;
        if (t == b) { sb[0] = excl; sb[1] = excl + v; }
    }
    fh[2 * t] = 0; fh[2 * t + 1] = 0;
    __syncthreads();
    int ebase = sb[0], eend = sb[1];
    for (int i = ebase + t; i < eend; i += 256) atomicAdd(&fh[bdata[i] >> 17], 1);
    __syncthreads();
    int a0 = fh[2 * t], a1 = fh[2 * t + 1];
    int psum = a0 + a1;
    int lane = t & 63, w = t >> 6;
    int v = psum;
    for (int off = 1; off < 64; off <<= 1) { int u = __shfl_up(v, off); if (lane >= off) v += u; }
    if (lane == 63) wt2[w] = v;
    __syncthreads();
    int wbase = 0;
    for (int i = 0; i < w; i++) wbase += wt2[i];
    int excl = wbase + v - psum;
    int e0 = excl, e1 = excl + a0;
    int n0 = (b << BSHIFT) + 2 * t, n1 = n0 + 1;
    if (n0 < N) row_off[n0] = ebase + e0;
    if (n1 < N) row_off[n1] = ebase + e1;
    fh[2 * t] = e0; fh[2 * t + 1] = e1;
    __syncthreads();
    for (int i = ebase + t; i < eend; i += 256) {
        unsigned vv = bdata[i];
        int dl = vv >> 17;
        int pos = atomicAdd(&fh[dl], 1);
        col_src[ebase + pos] = (int)(vv & 0x1FFFFu);
    }
}

// ---------------- Fused agg1 + gemm2 ----------------
// Block = 256 thr = 16 groups = 16 nodes. sH stride 74 (conflict-free reads).
__global__ __launch_bounds__(256) void k_agg1g2(const unsigned char* __restrict__ t1l8,
                                                const int* __restrict__ row_off,
                                                const int* __restrict__ col_src,
                                                const float* __restrict__ b1,
                                                const unsigned short* __restrict__ t1rb,
                                                const float* __restrict__ W2l,
                                                const float* __restrict__ W2r,
                                                const float* __restrict__ b2,
                                                int N,
                                                unsigned short* __restrict__ t2l,
                                                float* __restrict__ t2r) {
    __shared__ unsigned short sH[16 * HSTR];   // h tile [16 rows][k], stride 74
    __shared__ unsigned short sW2[64 * LSTR];  // [n][k], n: 0..31 W2l, 32..63 W2r
    int t = threadIdx.x;
    for (int i = t; i < 1024; i += 256) {
        int which = i >> 9;
        int rem = i & 511;
        int k = rem >> 3;
        int c4 = (rem & 7) * 4;
        f4 v = *(const f4*)&(which ? W2r : W2l)[k * 32 + c4];
        int nb = which * 32 + c4;
        sW2[(nb + 0) * LSTR + k] = f2bf(v[0]);
        sW2[(nb + 1) * LSTR + k] = f2bf(v[1]);
        sW2[(nb + 2) * LSTR + k] = f2bf(v[2]);
        sW2[(nb + 3) * LSTR + k] = f2bf(v[3]);
    }
    int g   = t >> 4;
    int gl  = t & 15;
    int gid = blockIdx.x * 16 + g;
    if (gid < N) {
        int beg = row_off[gid], end = row_off[gid + 1];
        f4 a0 = {0.f,0.f,0.f,0.f}, a1 = {0.f,0.f,0.f,0.f};
        f4 a2 = {0.f,0.f,0.f,0.f}, a3 = {0.f,0.f,0.f,0.f};
        int k = beg;
        for (; k + 7 < end; k += 8) {
            int i0 = col_src[k],     i1 = col_src[k + 1], i2 = col_src[k + 2], i3 = col_src[k + 3];
            int i4 = col_src[k + 4], i5 = col_src[k + 5], i6 = col_src[k + 6], i7 = col_src[k + 7];
            unsigned u0 = *(const unsigned*)&t1l8[(size_t)i0 * 64 + gl * 4];
            unsigned u1 = *(const unsigned*)&t1l8[(size_t)i1 * 64 + gl * 4];
            unsigned u2 = *(const unsigned*)&t1l8[(size_t)i2 * 64 + gl * 4];
            unsigned u3 = *(const unsigned*)&t1l8[(size_t)i3 * 64 + gl * 4];
            unsigned u4 = *(const unsigned*)&t1l8[(size_t)i4 * 64 + gl * 4];
            unsigned u5 = *(const unsigned*)&t1l8[(size_t)i5 * 64 + gl * 4];
            unsigned u6 = *(const unsigned*)&t1l8[(size_t)i6 * 64 + gl * 4];
            unsigned u7 = *(const unsigned*)&t1l8[(size_t)i7 * 64 + gl * 4];
            f2 l0 = __builtin_amdgcn_cvt_pk_f32_fp8(u0, false), h0 = __builtin_amdgcn_cvt_pk_f32_fp8(u0, true);
            f2 l1 = __builtin_amdgcn_cvt_pk_f32_fp8(u1, false), h1 = __builtin_amdgcn_cvt_pk_f32_fp8(u1, true);
            f2 l2 = __builtin_amdgcn_cvt_pk_f32_fp8(u2, false), h2 = __builtin_amdgcn_cvt_pk_f32_fp8(u2, true);
            f2 l3 = __builtin_amdgcn_cvt_pk_f32_fp8(u3, false), h3 = __builtin_amdgcn_cvt_pk_f32_fp8(u3, true);
            f2 l4 = __builtin_amdgcn_cvt_pk_f32_fp8(u4, false), h4 = __builtin_amdgcn_cvt_pk_f32_fp8(u4, true);
            f2 l5 = __builtin_amdgcn_cvt_pk_f32_fp8(u5, false), h5 = __builtin_amdgcn_cvt_pk_f32_fp8(u5, true);
            f2 l6 = __builtin_amdgcn_cvt_pk_f32_fp8(u6, false), h6 = __builtin_amdgcn_cvt_pk_f32_fp8(u6, true);
            f2 l7 = __builtin_amdgcn_cvt_pk_f32_fp8(u7, false), h7 = __builtin_amdgcn_cvt_pk_f32_fp8(u7, true);
            a0[0] += l0[0] + l4[0]; a0[1] += l0[1] + l4[1]; a0[2] += h0[0] + h4[0]; a0[3] += h0[1] + h4[1];
            a1[0] += l1[0] + l5[0]; a1[1] += l1[1] + l5[1]; a1[2] += h1[0] + h5[0]; a1[3] += h1[1] + h5[1];
            a2[0] += l2[0] + l6[0]; a2[1] += l2[1] + l6[1]; a2[2] += h2[0] + h6[0]; a2[3] += h2[1] + h6[1];
            a3[0] += l3[0] + l7[0]; a3[1] += l3[1] + l7[1]; a3[2] += h3[0] + h7[0]; a3[3] += h3[1] + h7[1];
        }
        for (; k + 3 < end; k += 4) {
            int i0 = col_src[k], i1 = col_src[k + 1], i2 = col_src[k + 2], i3 = col_src[k + 3];
            unsigned u0 = *(const unsigned*)&t1l8[(size_t)i0 * 64 + gl * 4];
            unsigned u1 = *(const unsigned*)&t1l8[(size_t)i1 * 64 + gl * 4];
            unsigned u2 = *(const unsigned*)&t1l8[(size_t)i2 * 64 + gl * 4];
            unsigned u3 = *(const unsigned*)&t1l8[(size_t)i3 * 64 + gl * 4];
            f2 l0 = __builtin_amdgcn_cvt_pk_f32_fp8(u0, false), h0 = __builtin_amdgcn_cvt_pk_f32_fp8(u0, true);
            f2 l1 = __builtin_amdgcn_cvt_pk_f32_fp8(u1, false), h1 = __builtin_amdgcn_cvt_pk_f32_fp8(u1, true);
            f2 l2 = __builtin_amdgcn_cvt_pk_f32_fp8(u2, false), h2 = __builtin_amdgcn_cvt_pk_f32_fp8(u2, true);
            f2 l3 = __builtin_amdgcn_cvt_pk_f32_fp8(u3, false), h3 = __builtin_amdgcn_cvt_pk_f32_fp8(u3, true);
            a0[0] += l0[0]; a0[1] += l0[1]; a0[2] += h0[0]; a0[3] += h0[1];
            a1[0] += l1[0]; a1[1] += l1[1]; a1[2] += h1[0]; a1[3] += h1[1];
            a2[0] += l2[0]; a2[1] += l2[1]; a2[2] += h2[0]; a2[3] += h2[1];
            a3[0] += l3[0]; a3[1] += l3[1]; a3[2] += h3[0]; a3[3] += h3[1];
        }
        for (; k < end; k++) {
            unsigned u0 = *(const unsigned*)&t1l8[(size_t)col_src[k] * 64 + gl * 4];
            f2 l0 = __builtin_amdgcn_cvt_pk_f32_fp8(u0, false), h0 = __builtin_amdgcn_cvt_pk_f32_fp8(u0, true);
            a0[0] += l0[0]; a0[1] += l0[1]; a0[2] += h0[0]; a0[3] += h0[1];
        }
        f4 s = (a0 + a1) + (a2 + a3);
        float deg = (float)(end - beg);
        float inv = deg > 0.f ? 1.f / deg : 0.f;
        us4 rb = *(const us4*)&t1rb[(size_t)gid * 64 + gl * 4];
        f4 bb = *(const f4*)&b1[gl * 4];
        us4 ob;
#pragma unroll
        for (int j = 0; j < 4; j++) {
            float v = s[j] * inv + bf2f(rb[j]) + bb[j];
            ob[j] = f2bf(v > 0.f ? v : 0.f);
        }
        *(us4*)&sH[g * HSTR + gl * 4] = ob;
    }
    __syncthreads();
    if (t < 64) {
        int lm = t & 15;
        int lk = (t >> 4) * 8;
        f4 acc[4] = {{0.f,0.f,0.f,0.f},{0.f,0.f,0.f,0.f},{0.f,0.f,0.f,0.f},{0.f,0.f,0.f,0.f}};
#pragma unroll
        for (int kh = 0; kh < 2; kh++) {
            bfrag a = *(const bfrag*)&sH[lm * HSTR + kh * 32 + lk];
#pragma unroll
            for (int nt = 0; nt < 4; nt++) {
                bfrag b = *(const bfrag*)&sW2[(nt * 16 + lm) * LSTR + kh * 32 + lk];
                acc[nt] = __builtin_amdgcn_mfma_f32_16x16x32_bf16(a, b, acc[nt], 0, 0, 0);
            }
        }
        int orow0 = blockIdx.x * 16 + (t >> 4) * 4;
#pragma unroll
        for (int j = 0; j < 4; j++) {
            int rr = orow0 + j;
            if (rr < N) {
#pragma unroll
                for (int nt = 0; nt < 2; nt++) {
                    t2l[(size_t)rr * 32 + nt * 16 + lm] = f2bf(acc[nt][j]);
                }
#pragma unroll
                for (int nt = 0; nt < 2; nt++) {
                    int c = nt * 16 + lm;
                    t2r[(size_t)rr * 32 + c] = acc[nt + 2][j] + b2[c];
                }
            }
        }
    }
}

// ---------------- Layer-2 gather: out = mean(t2l[nbrs]) + t2r ----------------
__global__ __launch_bounds__(256) void k_agg2(const unsigned short* __restrict__ t2l,
                                              const float* __restrict__ t2r,
                                              const int* __restrict__ row_off,
                                              const int* __restrict__ col_src,
                                              int N, float* __restrict__ out) {
    int gid = (blockIdx.x * blockDim.x + threadIdx.x) >> 4;
    int gl  = threadIdx.x & 15;
    if (gid >= N) return;
    int beg = row_off[gid], end = row_off[gid + 1];
    f2 a0 = {0.f,0.f}, a1 = {0.f,0.f}, a2 = {0.f,0.f}, a3 = {0.f,0.f};
    int k = beg;
    for (; k + 7 < end; k += 8) {
        int i0 = col_src[k],     i1 = col_src[k + 1], i2 = col_src[k + 2], i3 = col_src[k + 3];
        int i4 = col_src[k + 4], i5 = col_src[k + 5], i6 = col_src[k + 6], i7 = col_src[k + 7];
        unsigned u0 = *(const unsigned*)&t2l[(size_t)i0 * 32 + gl * 2];
        unsigned u1 = *(const unsigned*)&t2l[(size_t)i1 * 32 + gl * 2];
        unsigned u2 = *(const unsigned*)&t2l[(size_t)i2 * 32 + gl * 2];
        unsigned u3 = *(const unsigned*)&t2l[(size_t)i3 * 32 + gl * 2];
        unsigned u4 = *(const unsigned*)&t2l[(size_t)i4 * 32 + gl * 2];
        unsigned u5 = *(const unsigned*)&t2l[(size_t)i5 * 32 + gl * 2];
        unsigned u6 = *(const unsigned*)&t2l[(size_t)i6 * 32 + gl * 2];
        unsigned u7 = *(const unsigned*)&t2l[(size_t)i7 * 32 + gl * 2];
        a0[0] += bf2f((unsigned short)(u0 & 0xFFFFu)) + bf2f((unsigned short)(u4 & 0xFFFFu));
        a0[1] += bf2f((unsigned short)(u0 >> 16))     + bf2f((unsigned short)(u4 >> 16));
        a1[0] += bf2f((unsigned short)(u1 & 0xFFFFu)) + bf2f((unsigned short)(u5 & 0xFFFFu));
        a1[1] += bf2f((unsigned short)(u1 >> 16))     + bf2f((unsigned short)(u5 >> 16));
        a2[0] += bf2f((unsigned short)(u2 & 0xFFFFu)) + bf2f((unsigned short)(u6 & 0xFFFFu));
        a2[1] += bf2f((unsigned short)(u2 >> 16))     + bf2f((unsigned short)(u6 >> 16));
        a3[0] += bf2f((unsigned short)(u3 & 0xFFFFu)) + bf2f((unsigned short)(u7 & 0xFFFFu));
        a3[1] += bf2f((unsigned short)(u3 >> 16))     + bf2f((unsigned short)(u7 >> 16));
    }
    for (; k + 3 < end; k += 4) {
        int i0 = col_src[k], i1 = col_src[k + 1], i2 = col_src[k + 2], i3 = col_src[k + 3];
        unsigned u0 = *(const unsigned*)&t2l[(size_t)i0 * 32 + gl * 2];
        unsigned u1 = *(const unsigned*)&t2l[(size_t)i1 * 32 + gl * 2];
        unsigned u2 = *(const unsigned*)&t2l[(size_t)i2 * 32 + gl * 2];
        unsigned u3 = *(const unsigned*)&t2l[(size_t)i3 * 32 + gl * 2];
        a0[0] += bf2f((unsigned short)(u0 & 0xFFFFu)); a0[1] += bf2f((unsigned short)(u0 >> 16));
        a1[0] += bf2f((unsigned short)(u1 & 0xFFFFu)); a1[1] += bf2f((unsigned short)(u1 >> 16));
        a2[0] += bf2f((unsigned short)(u2 & 0xFFFFu)); a2[1] += bf2f((unsigned short)(u2 >> 16));
        a3[0] += bf2f((unsigned short)(u3 & 0xFFFFu)); a3[1] += bf2f((unsigned short)(u3 >> 16));
    }
    for (; k < end; k++) {
        unsigned u0 = *(const unsigned*)&t2l[(size_t)col_src[k] * 32 + gl * 2];
        a0[0] += bf2f((unsigned short)(u0 & 0xFFFFu)); a0[1] += bf2f((unsigned short)(u0 >> 16));
    }
    f2 s = (a0 + a1) + (a2 + a3);
    float deg = (float)(end - beg);
    float inv = deg > 0.f ? 1.f / deg : 0.f;
    f2 rr = *(const f2*)&t2r[(size_t)gid * 32 + gl * 2];
    f2 o = {s[0] * inv + rr[0], s[1] * inv + rr[1]};
    *(f2*)&out[(size_t)gid * 32 + gl * 2] = o;
}

extern "C" void kernel_launch(void* const* d_in, const int* in_sizes, int n_in,
                              void* d_out, int out_size, void* d_ws, size_t ws_size,
                              hipStream_t stream) {
    const float* x   = (const float*)d_in[0];
    const int*   ei  = (const int*)d_in[1];
    const float* W1l = (const float*)d_in[2];
    const float* b1  = (const float*)d_in[3];
    const float* W1r = (const float*)d_in[4];
    const float* W2l = (const float*)d_in[5];
    const float* b2  = (const float*)d_in[6];
    const float* W2r = (const float*)d_in[7];
    float* out = (float*)d_out;

    int N = in_sizes[0] / 64;
    int E = in_sizes[1] / 2;
    const int* src = ei;
    const int* dst = ei + E;
    int NB = (N + BSZ - 1) >> BSHIFT;   // 196

    char* ws = (char*)d_ws;
    size_t off = 0;
    auto alloc = [&](size_t bytes) { void* p = ws + off; off += (bytes + 255) & ~(size_t)255; return p; };
    int* cntmat      = (int*)alloc((size_t)NBLK * NB * 4);
    int* btot        = (int*)alloc((size_t)NB * 4);
    int* row_off     = (int*)alloc((size_t)(N + 1) * 4);
    int* col_src     = (int*)alloc((size_t)E * 4);
    unsigned int* bdata = (unsigned int*)alloc((size_t)E * 4);        // dead after CSR; reused as t2l
    unsigned char* t1l8 = (unsigned char*)alloc((size_t)N * 64);      // fp8
    unsigned short* t1rb = (unsigned short*)alloc((size_t)N * 64 * 2); // bf16; reused as t2r (per-row
                                                                       // read->write within same block)

    unsigned short* t2l = (unsigned short*)bdata;  // N*32*2 == E*4
    float* t2r          = (float*)t1rb;            // N*32*4 == t1rb size

    int chunk = (E + NBLK - 1) / NBLK;
    int gb = (N + 63) / 64;

    k_g1h<<<gb + NBLK, 256, 0, stream>>>(x, W1l, W1r, N, gb, t1l8, t1rb,
                                         dst, E, chunk, NB, cntmat);
    k_cscan<<<NB, 256, 0, stream>>>(cntmat, NB, E, N, btot, row_off);
    k_bscatter<<<NBLK, 256, 0, stream>>>(src, dst, E, chunk, NB, btot, cntmat, bdata);
    k_bucket_csr<<<NB, 256, 0, stream>>>(bdata, btot, NB, N, row_off, col_src);

    k_agg1g2<<<(N + 15) / 16, 256, 0, stream>>>(t1l8, row_off, col_src, b1, t1rb,
                                                W2l, W2r, b2, N, t2l, t2r);
    k_agg2<<<((size_t)N * 16 + 255) / 256, 256, 0, stream>>>(t2l, t2r, row_off, col_src, N, out);
}

// Round 17
// 129.341 us; speedup vs baseline: 1.0265x; 1.0265x over previous
//
#include <hip/hip_runtime.h>

// GraphSAGE 2-layer, fp32 in/out. N=100000, E=1.6M, D: 64 -> 64 -> 32.
// == R14 structure (best measured: 129.7 us) ==
// Transform-first on BOTH layers. t1l: fp8 (64 B rows), t2l: bf16 (64 B rows),
// t1r/h: bf16. GEMMs: bf16 MFMA 16x16x32. Aggs: 16-lane group per node,
// 8-deep independent gather chains (MSHR-bound floor, R6/R12/R13).
// bhist fused into gemm1 (block-split, 27.6 KB LDS); bscan removed (bscatter
// & bucket_csr recompute the 196-elem bucket-base scan per block).
// R15/R16 lesson: agg1+gemm2 fusion is net-negative (per-block W2 reload
// ~50 MB extra L2 reads + barrier straggler-wait + wave-0-only MFMA); the
// R15 LDS-sort bscatter cut its occupancy 8->4 blk/CU. Both reverted.

typedef __attribute__((ext_vector_type(4))) float f4;
typedef __attribute__((ext_vector_type(2))) float f2;
typedef __attribute__((ext_vector_type(4))) unsigned short us4;
typedef __attribute__((ext_vector_type(8))) unsigned short us8;
typedef __attribute__((ext_vector_type(8))) short bfrag;   // 8 bf16 (4 VGPRs)

#define BSHIFT 9
#define BSZ (1 << BSHIFT)   // 512 nodes per bucket
#define NBMAX 256
#define NBLK 512            // histogram/scatter blocks (cntmat rows)
#define LSTR 72             // LDS row stride in ushorts (144 B)

static __device__ inline unsigned short f2bf(float f) {
    union { float f; unsigned u; } v; v.f = f;
    unsigned u = v.u;
    u = (u + 0x7FFFu + ((u >> 16) & 1u)) >> 16;   // RNE
    return (unsigned short)u;
}
static __device__ inline float bf2f(unsigned short h) {
    union { unsigned u; float f; } v; v.u = ((unsigned)h) << 16; return v.f;
}

// ---------------- Fused GEMM1 + bhist ----------------
__global__ __launch_bounds__(256) void k_g1h(const float* __restrict__ x,
                                             const float* __restrict__ Wl,
                                             const float* __restrict__ Wr, int N, int gb,
                                             unsigned char* __restrict__ t1l8,
                                             unsigned short* __restrict__ t1rb,
                                             const int* __restrict__ dst, int E, int chunk,
                                             int NB, int* __restrict__ cntmat) {
    __shared__ unsigned short smem[64 * LSTR + 128 * LSTR];   // 27.6 KB
    int t = threadIdx.x;
    if ((int)blockIdx.x >= gb) {
        int* hist = (int*)smem;
        hist[t] = 0;
        __syncthreads();
        int bb = blockIdx.x - gb;
        int lo = bb * chunk, hi = min(lo + chunk, E);
        for (int e = lo + t; e < hi; e += 256) atomicAdd(&hist[dst[e] >> BSHIFT], 1);
        __syncthreads();
        if (t < NB) cntmat[bb * NB + t] = hist[t];
        return;
    }
    unsigned short* sX = smem;              // [64][LSTR]
    unsigned short* sW = smem + 64 * LSTR;  // [128][LSTR]
    int r0 = blockIdx.x * 64;
    for (int i = t; i < 2048; i += 256) {
        int which = i >> 10;
        int rem = i & 1023;
        int k = rem >> 4;
        int c4 = (rem & 15) * 4;
        f4 v = *(const f4*)&(which ? Wr : Wl)[k * 64 + c4];
        int nb = which * 64 + c4;
        sW[(nb + 0) * LSTR + k] = f2bf(v[0]);
        sW[(nb + 1) * LSTR + k] = f2bf(v[1]);
        sW[(nb + 2) * LSTR + k] = f2bf(v[2]);
        sW[(nb + 3) * LSTR + k] = f2bf(v[3]);
    }
    {
        int row = t >> 2;
        int q = (t & 3) * 16;
        bool valid = (r0 + row) < N;
#pragma unroll
        for (int j = 0; j < 4; j++) {
            f4 v = {0.f, 0.f, 0.f, 0.f};
            if (valid) v = *(const f4*)&x[(size_t)(r0 + row) * 64 + q + j * 4];
            us4 bv;
            bv[0] = f2bf(v[0]); bv[1] = f2bf(v[1]); bv[2] = f2bf(v[2]); bv[3] = f2bf(v[3]);
            *(us4*)&sX[row * LSTR + q + j * 4] = bv;
        }
    }
    __syncthreads();
    int wv = t >> 6;
    int l  = t & 63;
    int lm = l & 15;
    int lk = (l >> 4) * 8;
    f4 acc[8] = {{0.f,0.f,0.f,0.f},{0.f,0.f,0.f,0.f},{0.f,0.f,0.f,0.f},{0.f,0.f,0.f,0.f},
                 {0.f,0.f,0.f,0.f},{0.f,0.f,0.f,0.f},{0.f,0.f,0.f,0.f},{0.f,0.f,0.f,0.f}};
#pragma unroll
    for (int kh = 0; kh < 2; kh++) {
        bfrag a = *(const bfrag*)&sX[(wv * 16 + lm) * LSTR + kh * 32 + lk];
#pragma unroll
        for (int nt = 0; nt < 8; nt++) {
            bfrag b = *(const bfrag*)&sW[(nt * 16 + lm) * LSTR + kh * 32 + lk];
            acc[nt] = __builtin_amdgcn_mfma_f32_16x16x32_bf16(a, b, acc[nt], 0, 0, 0);
        }
    }
    int orow0 = r0 + wv * 16 + (l >> 4) * 4;
#pragma unroll
    for (int j = 0; j < 4; j++) {
        int rr = orow0 + j;
        if (rr < N) {
#pragma unroll
            for (int nt = 0; nt < 4; nt++) {
                float v = acc[nt][j];
                unsigned w8 = __builtin_amdgcn_cvt_pk_fp8_f32(v, v, 0u, false);
                t1l8[(size_t)rr * 64 + nt * 16 + lm] = (unsigned char)(w8 & 0xFFu);
            }
#pragma unroll
            for (int nt = 0; nt < 4; nt++) {
                t1rb[(size_t)rr * 64 + nt * 16 + lm] = f2bf(acc[nt + 4][j]);
            }
        }
    }
}

// ---------------- cscan ----------------
__global__ __launch_bounds__(256) void k_cscan(int* __restrict__ cntmat, int NB, int E, int N,
                                               int* __restrict__ btot, int* __restrict__ row_off) {
    __shared__ int wt[4];
    int b = blockIdx.x;
    int t = threadIdx.x;
    int v0 = cntmat[(2 * t) * NB + b];
    int v1 = cntmat[(2 * t + 1) * NB + b];
    int tsum = v0 + v1;
    int lane = t & 63, w = t >> 6;
    int p = tsum;
    for (int off = 1; off < 64; off <<= 1) { int u = __shfl_up(p, off); if (lane >= off) p += u; }
    if (lane == 63) wt[w] = p;
    __syncthreads();
    int wb = 0;
    for (int i = 0; i < w; i++) wb += wt[i];
    int excl = wb + p - tsum;
    cntmat[(2 * t) * NB + b] = excl;
    cntmat[(2 * t + 1) * NB + b] = excl + v0;
    if (t == 255) btot[b] = wb + p;
    if (b == 0 && t == 0) row_off[N] = E;
}

// ---------------- bscatter: single-pass ----------------
__global__ __launch_bounds__(256) void k_bscatter(const int* __restrict__ src, const int* __restrict__ dst,
                                                  int E, int chunk, int NB,
                                                  const int* __restrict__ btot,
                                                  const int* __restrict__ cntmat,
                                                  unsigned int* __restrict__ bdata) {
    __shared__ int lbase[NBMAX], lcur[NBMAX];
    __shared__ int wt[4];
    int t = threadIdx.x;
    int v = (t < NB) ? btot[t] : 0;
    int lane = t & 63, w = t >> 6;
    int p = v;
    for (int off = 1; off < 64; off <<= 1) { int u = __shfl_up(p, off); if (lane >= off) p += u; }
    if (lane == 63) wt[w] = p;
    __syncthreads();
    int wb = 0;
    for (int i = 0; i < w; i++) wb += wt[i];
    int excl = wb + p - v;
    if (t < NB) { lbase[t] = excl + cntmat[blockIdx.x * NB + t]; lcur[t] = 0; }
    __syncthreads();
    int lo = blockIdx.x * chunk, hi = min(lo + chunk, E);
    for (int e = lo + t; e < hi; e += 256) {
        int d = dst[e];
        int b = d >> BSHIFT;
        int pos = lbase[b] + atomicAdd(&lcur[b], 1);
        bdata[pos] = ((unsigned)(d & (BSZ - 1)) << 17) | (unsigned)src[e];  // src < 2^17
    }
}

// ---------------- bucket_csr ----------------
__global__ __launch_bounds__(256) void k_bucket_csr(const unsigned int* __restrict__ bdata,
                                                    const int* __restrict__ btot, int NB,
                                                    int N, int* __restrict__ row_off,
                                                    int* __restrict__ col_src) {
    __shared__ int fh[BSZ];
    __shared__ int wt1[4], wt2[4];
    __shared__ int sb[2];
    int t = threadIdx.x;
    int b = blockIdx.x;
    {
        int v = (t < NB) ? btot[t] : 0;
        int lane = t & 63, w = t >> 6;
        int p = v;
        for (int off = 1; off < 64; off <<= 1) { int u = __shfl_up(p, off); if (lane >= off) p += u; }
        if (lane == 63) wt1[w] = p;
        __syncthreads();
        int wb = 0;
        for (int i = 0; i < w; i++) wb += wt1[i];
        int excl = wb + p - v;
        if (t == b) { sb[0] = excl; sb[1] = excl + v; }
    }
    fh[2 * t] = 0; fh[2 * t + 1] = 0;
    __syncthreads();
    int ebase = sb[0], eend = sb[1];
    for (int i = ebase + t; i < eend; i += 256) atomicAdd(&fh[bdata[i] >> 17], 1);
    __syncthreads();
    int a0 = fh[2 * t], a1 = fh[2 * t + 1];
    int psum = a0 + a1;
    int lane = t & 63, w = t >> 6;
    int v = psum;
    for (int off = 1; off < 64; off <<= 1) { int u = __shfl_up(v, off); if (lane >= off) v += u; }
    if (lane == 63) wt2[w] = v;
    __syncthreads();
    int wbase = 0;
    for (int i = 0; i < w; i++) wbase += wt2[i];
    int excl = wbase + v - psum;
    int e0 = excl, e1 = excl + a0;
    int n0 = (b << BSHIFT) + 2 * t, n1 = n0 + 1;
    if (n0 < N) row_off[n0] = ebase + e0;
    if (n1 < N) row_off[n1] = ebase + e1;
    fh[2 * t] = e0; fh[2 * t + 1] = e1;
    __syncthreads();
    for (int i = ebase + t; i < eend; i += 256) {
        unsigned vv = bdata[i];
        int dl = vv >> 17;
        int pos = atomicAdd(&fh[dl], 1);
        col_src[ebase + pos] = (int)(vv & 0x1FFFFu);
    }
}

// ---------------- GEMM 2 (MFMA bf16): t2l(bf16) = h@W2l, t2r(f32) = h@W2r + b2 ----
__global__ __launch_bounds__(256) void k_gemm2(const unsigned short* __restrict__ hbf,
                                               const float* __restrict__ Wl,
                                               const float* __restrict__ Wr,
                                               const float* __restrict__ b2, int N,
                                               unsigned short* __restrict__ t2l,
                                               float* __restrict__ t2r) {
    __shared__ unsigned short sX[64 * LSTR];
    __shared__ unsigned short sW[64 * LSTR];
    int t = threadIdx.x;
    int r0 = blockIdx.x * 64;
    for (int i = t; i < 1024; i += 256) {
        int which = i >> 9;
        int rem = i & 511;
        int k = rem >> 3;
        int c4 = (rem & 7) * 4;
        f4 v = *(const f4*)&(which ? Wr : Wl)[k * 32 + c4];
        int nb = which * 32 + c4;
        sW[(nb + 0) * LSTR + k] = f2bf(v[0]);
        sW[(nb + 1) * LSTR + k] = f2bf(v[1]);
        sW[(nb + 2) * LSTR + k] = f2bf(v[2]);
        sW[(nb + 3) * LSTR + k] = f2bf(v[3]);
    }
    {
        int row = t >> 2;
        int q = (t & 3) * 16;
        us8 z = {0,0,0,0,0,0,0,0};
        us8 v0 = z, v1 = z;
        if (r0 + row < N) {
            v0 = *(const us8*)&hbf[(size_t)(r0 + row) * 64 + q];
            v1 = *(const us8*)&hbf[(size_t)(r0 + row) * 64 + q + 8];
        }
        *(us8*)&sX[row * LSTR + q] = v0;
        *(us8*)&sX[row * LSTR + q + 8] = v1;
    }
    __syncthreads();
    int wv = t >> 6;
    int l  = t & 63;
    int lm = l & 15;
    int lk = (l >> 4) * 8;
    f4 acc[4] = {{0.f,0.f,0.f,0.f},{0.f,0.f,0.f,0.f},{0.f,0.f,0.f,0.f},{0.f,0.f,0.f,0.f}};
#pragma unroll
    for (int kh = 0; kh < 2; kh++) {
        bfrag a = *(const bfrag*)&sX[(wv * 16 + lm) * LSTR + kh * 32 + lk];
#pragma unroll
        for (int nt = 0; nt < 4; nt++) {
            bfrag b = *(const bfrag*)&sW[(nt * 16 + lm) * LSTR + kh * 32 + lk];
            acc[nt] = __builtin_amdgcn_mfma_f32_16x16x32_bf16(a, b, acc[nt], 0, 0, 0);
        }
    }
    int orow0 = r0 + wv * 16 + (l >> 4) * 4;
#pragma unroll
    for (int j = 0; j < 4; j++) {
        int rr = orow0 + j;
        if (rr < N) {
#pragma unroll
            for (int nt = 0; nt < 2; nt++) {
                t2l[(size_t)rr * 32 + nt * 16 + lm] = f2bf(acc[nt][j]);
            }
#pragma unroll
            for (int nt = 0; nt < 2; nt++) {
                int c = nt * 16 + lm;
                t2r[(size_t)rr * 32 + c] = acc[nt + 2][j] + b2[c];
            }
        }
    }
}

// ---------------- Layer-1 gather: h(bf16) = relu(mean(t1l[nbrs]) + t1r + b1) ------
__global__ __launch_bounds__(256) void k_agg1(const unsigned char* __restrict__ t1l8,
                                              const int* __restrict__ row_off,
                                              const int* __restrict__ col_src,
                                              const float* __restrict__ b1,
                                              const unsigned short* __restrict__ t1rb,
                                              int N, unsigned short* __restrict__ hbf) {
    int gid = (blockIdx.x * blockDim.x + threadIdx.x) >> 4;
    int gl  = threadIdx.x & 15;
    if (gid >= N) return;
    int beg = row_off[gid], end = row_off[gid + 1];
    f4 a0 = {0.f,0.f,0.f,0.f}, a1 = {0.f,0.f,0.f,0.f};
    f4 a2 = {0.f,0.f,0.f,0.f}, a3 = {0.f,0.f,0.f,0.f};
    int k = beg;
    for (; k + 7 < end; k += 8) {
        int i0 = col_src[k],     i1 = col_src[k + 1], i2 = col_src[k + 2], i3 = col_src[k + 3];
        int i4 = col_src[k + 4], i5 = col_src[k + 5], i6 = col_src[k + 6], i7 = col_src[k + 7];
        unsigned u0 = *(const unsigned*)&t1l8[(size_t)i0 * 64 + gl * 4];
        unsigned u1 = *(const unsigned*)&t1l8[(size_t)i1 * 64 + gl * 4];
        unsigned u2 = *(const unsigned*)&t1l8[(size_t)i2 * 64 + gl * 4];
        unsigned u3 = *(const unsigned*)&t1l8[(size_t)i3 * 64 + gl * 4];
        unsigned u4 = *(const unsigned*)&t1l8[(size_t)i4 * 64 + gl * 4];
        unsigned u5 = *(const unsigned*)&t1l8[(size_t)i5 * 64 + gl * 4];
        unsigned u6 = *(const unsigned*)&t1l8[(size_t)i6 * 64 + gl * 4];
        unsigned u7 = *(const unsigned*)&t1l8[(size_t)i7 * 64 + gl * 4];
        f2 l0 = __builtin_amdgcn_cvt_pk_f32_fp8(u0, false), h0 = __builtin_amdgcn_cvt_pk_f32_fp8(u0, true);
        f2 l1 = __builtin_amdgcn_cvt_pk_f32_fp8(u1, false), h1 = __builtin_amdgcn_cvt_pk_f32_fp8(u1, true);
        f2 l2 = __builtin_amdgcn_cvt_pk_f32_fp8(u2, false), h2 = __builtin_amdgcn_cvt_pk_f32_fp8(u2, true);
        f2 l3 = __builtin_amdgcn_cvt_pk_f32_fp8(u3, false), h3 = __builtin_amdgcn_cvt_pk_f32_fp8(u3, true);
        f2 l4 = __builtin_amdgcn_cvt_pk_f32_fp8(u4, false), h4 = __builtin_amdgcn_cvt_pk_f32_fp8(u4, true);
        f2 l5 = __builtin_amdgcn_cvt_pk_f32_fp8(u5, false), h5 = __builtin_amdgcn_cvt_pk_f32_fp8(u5, true);
        f2 l6 = __builtin_amdgcn_cvt_pk_f32_fp8(u6, false), h6 = __builtin_amdgcn_cvt_pk_f32_fp8(u6, true);
        f2 l7 = __builtin_amdgcn_cvt_pk_f32_fp8(u7, false), h7 = __builtin_amdgcn_cvt_pk_f32_fp8(u7, true);
        a0[0] += l0[0] + l4[0]; a0[1] += l0[1] + l4[1]; a0[2] += h0[0] + h4[0]; a0[3] += h0[1] + h4[1];
        a1[0] += l1[0] + l5[0]; a1[1] += l1[1] + l5[1]; a1[2] += h1[0] + h5[0]; a1[3] += h1[1] + h5[1];
        a2[0] += l2[0] + l6[0]; a2[1] += l2[1] + l6[1]; a2[2] += h2[0] + h6[0]; a2[3] += h2[1] + h6[1];
        a3[0] += l3[0] + l7[0]; a3[1] += l3[1] + l7[1]; a3[2] += h3[0] + h7[0]; a3[3] += h3[1] + h7[1];
    }
    for (; k + 3 < end; k += 4) {
        int i0 = col_src[k], i1 = col_src[k + 1], i2 = col_src[k + 2], i3 = col_src[k + 3];
        unsigned u0 = *(const unsigned*)&t1l8[(size_t)i0 * 64 + gl * 4];
        unsigned u1 = *(const unsigned*)&t1l8[(size_t)i1 * 64 + gl * 4];
        unsigned u2 = *(const unsigned*)&t1l8[(size_t)i2 * 64 + gl * 4];
        unsigned u3 = *(const unsigned*)&t1l8[(size_t)i3 * 64 + gl * 4];
        f2 l0 = __builtin_amdgcn_cvt_pk_f32_fp8(u0, false), h0 = __builtin_amdgcn_cvt_pk_f32_fp8(u0, true);
        f2 l1 = __builtin_amdgcn_cvt_pk_f32_fp8(u1, false), h1 = __builtin_amdgcn_cvt_pk_f32_fp8(u1, true);
        f2 l2 = __builtin_amdgcn_cvt_pk_f32_fp8(u2, false), h2 = __builtin_amdgcn_cvt_pk_f32_fp8(u2, true);
        f2 l3 = __builtin_amdgcn_cvt_pk_f32_fp8(u3, false), h3 = __builtin_amdgcn_cvt_pk_f32_fp8(u3, true);
        a0[0] += l0[0]; a0[1] += l0[1]; a0[2] += h0[0]; a0[3] += h0[1];
        a1[0] += l1[0]; a1[1] += l1[1]; a1[2] += h1[0]; a1[3] += h1[1];
        a2[0] += l2[0]; a2[1] += l2[1]; a2[2] += h2[0]; a2[3] += h2[1];
        a3[0] += l3[0]; a3[1] += l3[1]; a3[2] += h3[0]; a3[3] += h3[1];
    }
    for (; k < end; k++) {
        unsigned u0 = *(const unsigned*)&t1l8[(size_t)col_src[k] * 64 + gl * 4];
        f2 l0 = __builtin_amdgcn_cvt_pk_f32_fp8(u0, false), h0 = __builtin_amdgcn_cvt_pk_f32_fp8(u0, true);
        a0[0] += l0[0]; a0[1] += l0[1]; a0[2] += h0[0]; a0[3] += h0[1];
    }
    f4 s = (a0 + a1) + (a2 + a3);
    float deg = (float)(end - beg);
    float inv = deg > 0.f ? 1.f / deg : 0.f;
    us4 rb = *(const us4*)&t1rb[(size_t)gid * 64 + gl * 4];
    f4 bb = *(const f4*)&b1[gl * 4];
    us4 ob;
#pragma unroll
    for (int j = 0; j < 4; j++) {
        float v = s[j] * inv + bf2f(rb[j]) + bb[j];
        ob[j] = f2bf(v > 0.f ? v : 0.f);
    }
    *(us4*)&hbf[(size_t)gid * 64 + gl * 4] = ob;
}

// ---------------- Layer-2 gather: out = mean(t2l[nbrs]) + t2r ----------------
__global__ __launch_bounds__(256) void k_agg2(const unsigned short* __restrict__ t2l,
                                              const float* __restrict__ t2r,
                                              const int* __restrict__ row_off,
                                              const int* __restrict__ col_src,
                                              int N, float* __restrict__ out) {
    int gid = (blockIdx.x * blockDim.x + threadIdx.x) >> 4;
    int gl  = threadIdx.x & 15;
    if (gid >= N) return;
    int beg = row_off[gid], end = row_off[gid + 1];
    f2 a0 = {0.f,0.f}, a1 = {0.f,0.f}, a2 = {0.f,0.f}, a3 = {0.f,0.f};
    int k = beg;
    for (; k + 7 < end; k += 8) {
        int i0 = col_src[k],     i1 = col_src[k + 1], i2 = col_src[k + 2], i3 = col_src[k + 3];
        int i4 = col_src[k + 4], i5 = col_src[k + 5], i6 = col_src[k + 6], i7 = col_src[k + 7];
        unsigned u0 = *(const unsigned*)&t2l[(size_t)i0 * 32 + gl * 2];
        unsigned u1 = *(const unsigned*)&t2l[(size_t)i1 * 32 + gl * 2];
        unsigned u2 = *(const unsigned*)&t2l[(size_t)i2 * 32 + gl * 2];
        unsigned u3 = *(const unsigned*)&t2l[(size_t)i3 * 32 + gl * 2];
        unsigned u4 = *(const unsigned*)&t2l[(size_t)i4 * 32 + gl * 2];
        unsigned u5 = *(const unsigned*)&t2l[(size_t)i5 * 32 + gl * 2];
        unsigned u6 = *(const unsigned*)&t2l[(size_t)i6 * 32 + gl * 2];
        unsigned u7 = *(const unsigned*)&t2l[(size_t)i7 * 32 + gl * 2];
        a0[0] += bf2f((unsigned short)(u0 & 0xFFFFu)) + bf2f((unsigned short)(u4 & 0xFFFFu));
        a0[1] += bf2f((unsigned short)(u0 >> 16))     + bf2f((unsigned short)(u4 >> 16));
        a1[0] += bf2f((unsigned short)(u1 & 0xFFFFu)) + bf2f((unsigned short)(u5 & 0xFFFFu));
        a1[1] += bf2f((unsigned short)(u1 >> 16))     + bf2f((unsigned short)(u5 >> 16));
        a2[0] += bf2f((unsigned short)(u2 & 0xFFFFu)) + bf2f((unsigned short)(u6 & 0xFFFFu));
        a2[1] += bf2f((unsigned short)(u2 >> 16))     + bf2f((unsigned short)(u6 >> 16));
        a3[0] += bf2f((unsigned short)(u3 & 0xFFFFu)) + bf2f((unsigned short)(u7 & 0xFFFFu));
        a3[1] += bf2f((unsigned short)(u3 >> 16))     + bf2f((unsigned short)(u7 >> 16));
    }
    for (; k + 3 < end; k += 4) {
        int i0 = col_src[k], i1 = col_src[k + 1], i2 = col_src[k + 2], i3 = col_src[k + 3];
        unsigned u0 = *(const unsigned*)&t2l[(size_t)i0 * 32 + gl * 2];
        unsigned u1 = *(const unsigned*)&t2l[(size_t)i1 * 32 + gl * 2];
        unsigned u2 = *(const unsigned*)&t2l[(size_t)i2 * 32 + gl * 2];
        unsigned u3 = *(const unsigned*)&t2l[(size_t)i3 * 32 + gl * 2];
        a0[0] += bf2f((unsigned short)(u0 & 0xFFFFu)); a0[1] += bf2f((unsigned short)(u0 >> 16));
        a1[0] += bf2f((unsigned short)(u1 & 0xFFFFu)); a1[1] += bf2f((unsigned short)(u1 >> 16));
        a2[0] += bf2f((unsigned short)(u2 & 0xFFFFu)); a2[1] += bf2f((unsigned short)(u2 >> 16));
        a3[0] += bf2f((unsigned short)(u3 & 0xFFFFu)); a3[1] += bf2f((unsigned short)(u3 >> 16));
    }
    for (; k < end; k++) {
        unsigned u0 = *(const unsigned*)&t2l[(size_t)col_src[k] * 32 + gl * 2];
        a0[0] += bf2f((unsigned short)(u0 & 0xFFFFu)); a0[1] += bf2f((unsigned short)(u0 >> 16));
    }
    f2 s = (a0 + a1) + (a2 + a3);
    float deg = (float)(end - beg);
    float inv = deg > 0.f ? 1.f / deg : 0.f;
    f2 rr = *(const f2*)&t2r[(size_t)gid * 32 + gl * 2];
    f2 o = {s[0] * inv + rr[0], s[1] * inv + rr[1]};
    *(f2*)&out[(size_t)gid * 32 + gl * 2] = o;
}

extern "C" void kernel_launch(void* const* d_in, const int* in_sizes, int n_in,
                              void* d_out, int out_size, void* d_ws, size_t ws_size,
                              hipStream_t stream) {
    const float* x   = (const float*)d_in[0];
    const int*   ei  = (const int*)d_in[1];
    const float* W1l = (const float*)d_in[2];
    const float* b1  = (const float*)d_in[3];
    const float* W1r = (const float*)d_in[4];
    const float* W2l = (const float*)d_in[5];
    const float* b2  = (const float*)d_in[6];
    const float* W2r = (const float*)d_in[7];
    float* out = (float*)d_out;

    int N = in_sizes[0] / 64;
    int E = in_sizes[1] / 2;
    const int* src = ei;
    const int* dst = ei + E;
    int NB = (N + BSZ - 1) >> BSHIFT;   // 196

    char* ws = (char*)d_ws;
    size_t off = 0;
    auto alloc = [&](size_t bytes) { void* p = ws + off; off += (bytes + 255) & ~(size_t)255; return p; };
    int* cntmat      = (int*)alloc((size_t)NBLK * NB * 4);
    int* btot        = (int*)alloc((size_t)NB * 4);
    int* row_off     = (int*)alloc((size_t)(N + 1) * 4);
    int* col_src     = (int*)alloc((size_t)E * 4);
    unsigned int* bdata = (unsigned int*)alloc((size_t)E * 4);        // dead after CSR; reused as t2l
    unsigned char* t1l8 = (unsigned char*)alloc((size_t)N * 64);      // fp8
    unsigned short* t1rb = (unsigned short*)alloc((size_t)N * 64 * 2); // bf16; dead after agg1 -> t2r
    unsigned short* hbf  = (unsigned short*)alloc((size_t)N * 64 * 2); // h bf16

    unsigned short* t2l = (unsigned short*)bdata;  // N*32*2 == E*4
    float* t2r          = (float*)t1rb;            // N*32*4 == t1rb size

    int chunk = (E + NBLK - 1) / NBLK;
    int gb = (N + 63) / 64;

    k_g1h<<<gb + NBLK, 256, 0, stream>>>(x, W1l, W1r, N, gb, t1l8, t1rb,
                                         dst, E, chunk, NB, cntmat);
    k_cscan<<<NB, 256, 0, stream>>>(cntmat, NB, E, N, btot, row_off);
    k_bscatter<<<NBLK, 256, 0, stream>>>(src, dst, E, chunk, NB, btot, cntmat, bdata);
    k_bucket_csr<<<NB, 256, 0, stream>>>(bdata, btot, NB, N, row_off, col_src);

    k_agg1<<<((size_t)N * 16 + 255) / 256, 256, 0, stream>>>(t1l8, row_off, col_src, b1, t1rb, N, hbf);
    k_gemm2<<<gb, 256, 0, stream>>>(hbf, W2l, W2r, b2, N, t2l, t2r);
    k_agg2<<<((size_t)N * 16 + 255) / 256, 256, 0, stream>>>(t2l, t2r, row_off, col_src, N, out);
}